// Round 14
// baseline (344.050 us; speedup 1.0000x reference)
//
#include <hip/hip_runtime.h>

#define D 128
#define KN 32

typedef __bf16 bf16x8 __attribute__((ext_vector_type(8)));
typedef float f32x4 __attribute__((ext_vector_type(4)));

// --- f32 -> bf16 (RNE) packing helpers -------------------------------------
__device__ __forceinline__ unsigned bfpack2(float a, float b) {
  unsigned ua = __float_as_uint(a), ub = __float_as_uint(b);
  ua += 0x7FFFu + ((ua >> 16) & 1u);
  ub += 0x7FFFu + ((ub >> 16) & 1u);
  return (ua >> 16) | (ub & 0xFFFF0000u);
}
__device__ __forceinline__ uint4 pack8(const float4& a, const float4& b) {
  uint4 r;
  r.x = bfpack2(a.x, a.y); r.y = bfpack2(a.z, a.w);
  r.z = bfpack2(b.x, b.y); r.w = bfpack2(b.z, b.w);
  return r;
}

// LDS-only barrier: orders LDS producer/consumer across waves WITHOUT the
// vmcnt(0) drain hipcc emits for __syncthreads(). Keeps prefetch global
// loads in flight across phase boundaries. sched_barrier(0) per rule #18.
__device__ __forceinline__ void lgkm_barrier() {
  __builtin_amdgcn_sched_barrier(0);
  asm volatile("s_waitcnt lgkmcnt(0)" ::: "memory");
  __builtin_amdgcn_s_barrier();
  __builtin_amdgcn_sched_barrier(0);
}

// LDS chunk layout (A and B tiles): buf[row*16 + (slot ^ (row&7))] holds bf16
// of cols slot*8..slot*8+7 of `row`. XOR swizzle -> conflict-free b128 reads.

// 512-thread stager (base_mfma): 128 rows, 2048 chunks -> 4/thread.
__device__ __forceinline__ void stage128_512(const float* __restrict__ src, int nrows,
                                             uint4* buf, int tid) {
  float4 v[4][2];
  #pragma unroll
  for (int i = 0; i < 4; ++i) {
    const int c = i * 512 + tid;
    const int row = c >> 4, slot = c & 15;
    if (row < nrows) {
      const float4* p = (const float4*)(src + (size_t)row * D + slot * 8);
      v[i][0] = p[0]; v[i][1] = p[1];
    } else {
      v[i][0] = make_float4(0.f, 0.f, 0.f, 0.f);
      v[i][1] = make_float4(0.f, 0.f, 0.f, 0.f);
    }
  }
  #pragma unroll
  for (int i = 0; i < 4; ++i) {
    const int c = i * 512 + tid;
    const int row = c >> 4, slot = c & 15;
    buf[row * 16 + (slot ^ (row & 7))] = pack8(v[i][0], v[i][1]);
  }
}

// 256-thread stager: 128 rows (Wn), 2048 chunks -> 8/thread.
__device__ __forceinline__ void stage128_256(const float* __restrict__ src,
                                             uint4* buf, int tid) {
  #pragma unroll
  for (int i = 0; i < 8; ++i) {
    const int c = i * 256 + tid;
    const int row = c >> 4, slot = c & 15;
    const float4* p = (const float4*)(src + (size_t)row * D + slot * 8);
    buf[row * 16 + (slot ^ (row & 7))] = pack8(p[0], p[1]);
  }
}

// 256-thread pipelined stager for the 64-row A-tile: issue / commit halves.
__device__ __forceinline__ void stage64_load(const float* __restrict__ src, int tid,
                                             float4 v[4][2]) {
  #pragma unroll
  for (int i = 0; i < 4; ++i) {
    const int c = i * 256 + tid;
    const int row = c >> 4, slot = c & 15;
    const float4* p = (const float4*)(src + (size_t)row * D + slot * 8);
    v[i][0] = p[0]; v[i][1] = p[1];
  }
}
__device__ __forceinline__ void stage64_write(uint4* buf, int tid,
                                              const float4 v[4][2]) {
  #pragma unroll
  for (int i = 0; i < 4; ++i) {
    const int c = i * 256 + tid;
    const int row = c >> 4, slot = c & 15;
    buf[row * 16 + (slot ^ (row & 7))] = pack8(v[i][0], v[i][1]);
  }
}

// base[r,e] = sum_d x[r,d]*Wx[e,d] + bx[e]+bn[e]+bw[e]  -> d_out  (unchanged)
__global__ __launch_bounds__(512, 4) void base_mfma(
    const float* __restrict__ x, const float* __restrict__ Wx,
    const float* __restrict__ bx, const float* __restrict__ bn,
    const float* __restrict__ bw, float* __restrict__ out, int N)
{
  __shared__ uint4 Bb[2048];
  __shared__ uint4 Ab[2048];
  __shared__ float bvec[D];
  const int tid = threadIdx.x;

  stage128_512(Wx, 128, Bb, tid);
  if (tid < D) bvec[tid] = bx[tid] + bn[tid] + bw[tid];

  const int lane = tid & 63, li = lane & 15, g = lane >> 4;
  const int wv = tid >> 6, rq = wv >> 1, ch = wv & 1;
  const int ntiles = (N + 127) >> 7;

  for (int t = blockIdx.x; t < ntiles; t += gridDim.x) {
    const int r0t = t << 7;
    __syncthreads();
    stage128_512(x + (size_t)r0t * D, N - r0t, Ab, tid);
    __syncthreads();

    f32x4 acc[2][4];
    #pragma unroll
    for (int i = 0; i < 2; ++i)
      #pragma unroll
      for (int j = 0; j < 4; ++j) acc[i][j] = (f32x4){0.f, 0.f, 0.f, 0.f};

    #pragma unroll
    for (int kb = 0; kb < 4; ++kb) {
      const int slot = kb * 4 + g;
      const int r0 = rq * 32 + li, r1 = r0 + 16;
      const bf16x8 a0 = __builtin_bit_cast(bf16x8, Ab[r0 * 16 + (slot ^ (r0 & 7))]);
      const bf16x8 a1 = __builtin_bit_cast(bf16x8, Ab[r1 * 16 + (slot ^ (r1 & 7))]);
      #pragma unroll
      for (int ct = 0; ct < 4; ++ct) {
        const int e = ch * 64 + ct * 16 + li;
        const bf16x8 b = __builtin_bit_cast(bf16x8, Bb[e * 16 + (slot ^ (e & 7))]);
        acc[0][ct] = __builtin_amdgcn_mfma_f32_16x16x32_bf16(a0, b, acc[0][ct], 0, 0, 0);
        acc[1][ct] = __builtin_amdgcn_mfma_f32_16x16x32_bf16(a1, b, acc[1][ct], 0, 0, 0);
      }
    }

    #pragma unroll
    for (int rt = 0; rt < 2; ++rt) {
      #pragma unroll
      for (int reg = 0; reg < 4; ++reg) {
        const int r = r0t + rq * 32 + rt * 16 + 4 * g + reg;
        if (r < N) {
          #pragma unroll
          for (int ct = 0; ct < 4; ++ct) {
            const int e = ch * 64 + ct * 16 + li;
            out[(size_t)r * D + e] = acc[rt][ct][reg] + bvec[e];
          }
        }
      }
    }
  }
}

// Fused: 2 nodes/iter, 256 threads, 3 blocks/CU, depth-1 prefetch + lgkm-only
// barriers (R9 schedule). NEW vs R9: loop-invariant hoisting — B-fragments
// for kb=0,1 (8 x uint4) and wwv/wlv kept in registers across iterations,
// cutting 8 b128 + 8 b32 LDS reads and ~30 addressing VALU per thread-iter.
__global__ __launch_bounds__(256, 3) void gnn_mfma(
    const float* __restrict__ x_nb, const float* __restrict__ weight,
    const float* __restrict__ Wn, const float* __restrict__ Ww,
    const float* __restrict__ Wl, float* __restrict__ out, int N)
{
  __shared__ uint4 Bb[2048];       // Wn bf16, 32 KB
  __shared__ uint4 Ab[1024];       // x_nb tile (2 nodes x 32 nbrs), 16 KB
  __shared__ float basel[2 * D];
  __shared__ float wwl[D], wll[D];
  __shared__ float wgt[2 * KN];
  __shared__ float spart[2][2][KN];
  __shared__ float attnl[2 * KN];
  const int tid = threadIdx.x;

  stage128_256(Wn, Bb, tid);
  if (tid < D) { wwl[tid] = Ww[tid]; wll[tid] = Wl[tid]; }

  const int lane = tid & 63, li = lane & 15, g = lane >> 4;
  const int wv = tid >> 6, rq = wv >> 1, ch = wv & 1;   // node = rq, e-half = ch
  const int ntiles = N >> 1;                             // 25000
  const int gr = gridDim.x;

  float4 v[4][2];
  float basev = 0.f, wgtv = 0.f;

  int t = blockIdx.x;
  {  // prologue: load + commit tile t0
    stage64_load(x_nb + (size_t)(2 * t) * KN * D, tid, v);
    basev = out[(size_t)(2 * t) * D + tid];
    if (tid < 2 * KN) wgtv = weight[(size_t)(2 * t) * KN + tid];
    stage64_write(Ab, tid, v);
    basel[tid] = basev;
    if (tid < 2 * KN) wgt[tid] = wgtv;
  }
  __syncthreads();

  // Loop-invariant hoists (after Wn/wwl/wll are staged): half the B-frags
  // (kb = 0,1) + score weights. +40 VGPR, removes per-iter LDS re-reads.
  uint4 Bfr[2][4];
  float wwv[4], wlv[4];
  #pragma unroll
  for (int ct = 0; ct < 4; ++ct) {
    const int e = ch * 64 + ct * 16 + li;
    #pragma unroll
    for (int kb = 0; kb < 2; ++kb) {
      const int slot = kb * 4 + g;
      Bfr[kb][ct] = Bb[e * 16 + (slot ^ (e & 7))];
    }
    wwv[ct] = wwl[e];
    wlv[ct] = wll[e];
  }

  for (; t < ntiles; t += gr) {
    const int tn = t + gr;
    const bool have_next = (tn < ntiles);
    if (have_next) {  // issue next tile's loads; consumed at the commit below
      stage64_load(x_nb + (size_t)(2 * tn) * KN * D, tid, v);
      basev = out[(size_t)(2 * tn) * D + tid];
      if (tid < 2 * KN) wgtv = weight[(size_t)(2 * tn) * KN + tid];
    }

    // --- MFMA: node rq rows (32), cols ch*64..+63 ---
    f32x4 acc[2][4];
    #pragma unroll
    for (int i = 0; i < 2; ++i)
      #pragma unroll
      for (int j = 0; j < 4; ++j) acc[i][j] = (f32x4){0.f, 0.f, 0.f, 0.f};

    #pragma unroll
    for (int kb = 0; kb < 4; ++kb) {
      const int slot = kb * 4 + g;
      const int r0 = rq * 32 + li, r1 = r0 + 16;
      const bf16x8 a0 = __builtin_bit_cast(bf16x8, Ab[r0 * 16 + (slot ^ (r0 & 7))]);
      const bf16x8 a1 = __builtin_bit_cast(bf16x8, Ab[r1 * 16 + (slot ^ (r1 & 7))]);
      #pragma unroll
      for (int ct = 0; ct < 4; ++ct) {
        const int e = ch * 64 + ct * 16 + li;
        const uint4 bu = (kb < 2) ? Bfr[kb & 1][ct]
                                  : Bb[e * 16 + (slot ^ (e & 7))];
        const bf16x8 b = __builtin_bit_cast(bf16x8, bu);
        acc[0][ct] = __builtin_amdgcn_mfma_f32_16x16x32_bf16(a0, b, acc[0][ct], 0, 0, 0);
        acc[1][ct] = __builtin_amdgcn_mfma_f32_16x16x32_bf16(a1, b, acc[1][ct], 0, 0, 0);
      }
    }

    // --- scores: s[k] = sum_e leaky(n_s + base + w*Ww) * Wl ---
    float bvv[4];
    #pragma unroll
    for (int ct = 0; ct < 4; ++ct) {
      const int e = ch * 64 + ct * 16 + li;
      bvv[ct] = basel[rq * D + e];
    }
    #pragma unroll
    for (int rt = 0; rt < 2; ++rt) {
      #pragma unroll
      for (int reg = 0; reg < 4; ++reg) {
        const int k = rt * 16 + 4 * g + reg;
        const float wk = wgt[rq * KN + k];
        float p = 0.f;
        #pragma unroll
        for (int ct = 0; ct < 4; ++ct) {
          float h = acc[rt][ct][reg] + bvv[ct] + wk * wwv[ct];
          h = fmaxf(h, 0.1f * h);            // LeakyReLU(0.1)
          p = fmaf(h, wlv[ct], p);
        }
        p += __shfl_xor(p, 1);
        p += __shfl_xor(p, 2);
        p += __shfl_xor(p, 4);
        p += __shfl_xor(p, 8);
        if (li == 0) spart[ch][rq][k] = p;
      }
    }
    lgkm_barrier();   // spart visible; prefetch loads stay in flight

    // --- softmax over K=32 per node (wave 0 handles both nodes) ---
    if (tid < 64) {
      const int node = tid >> 5, k = tid & 31;
      const float s = spart[0][node][k] + spart[1][node][k];
      float mx = s;
      #pragma unroll
      for (int m = 16; m >= 1; m >>= 1) mx = fmaxf(mx, __shfl_xor(mx, m));
      const float pe = __expf(s - mx);
      float sum = pe;
      #pragma unroll
      for (int m = 16; m >= 1; m >>= 1) sum += __shfl_xor(sum, m);
      attnl[node * KN + k] = pe / sum;
    }
    lgkm_barrier();

    // --- epilogue: out[n,c] = sum_k attn[k] * bf16_lds(x_nb)[k][c] ---
    if (wv < 2) {
      const int node = wv;
      const int slot = lane & 15, kg = lane >> 4;
      float p8[8];
      #pragma unroll
      for (int j = 0; j < 8; ++j) p8[j] = 0.f;
      #pragma unroll
      for (int kk = 0; kk < 8; ++kk) {
        const int k = kg * 8 + kk;
        const int row = node * KN + k;
        const uint4 u = Ab[row * 16 + (slot ^ kk)];
        const float a = attnl[node * KN + k];
        const unsigned uw[4] = {u.x, u.y, u.z, u.w};
        #pragma unroll
        for (int q = 0; q < 4; ++q) {
          p8[2 * q]     = fmaf(a, __uint_as_float(uw[q] << 16), p8[2 * q]);
          p8[2 * q + 1] = fmaf(a, __uint_as_float(uw[q] & 0xFFFF0000u), p8[2 * q + 1]);
        }
      }
      #pragma unroll
      for (int j = 0; j < 8; ++j) p8[j] += __shfl_xor(p8[j], 16);
      #pragma unroll
      for (int j = 0; j < 8; ++j) p8[j] += __shfl_xor(p8[j], 32);
      if (kg == 0) {
        float* o = out + (size_t)(2 * t + node) * D + slot * 8;
        *(float4*)(o)     = make_float4(p8[0], p8[1], p8[2], p8[3]);
        *(float4*)(o + 4) = make_float4(p8[4], p8[5], p8[6], p8[7]);
      }
    }
    lgkm_barrier();   // all Ab/attnl reads complete

    if (have_next) {  // commit next tile (compiler's vmcnt wait lands here)
      stage64_write(Ab, tid, v);
      basel[tid] = basev;
      if (tid < 2 * KN) wgt[tid] = wgtv;
    }
    lgkm_barrier();
  }
}

extern "C" void kernel_launch(void* const* d_in, const int* in_sizes, int n_in,
                              void* d_out, int out_size, void* d_ws, size_t ws_size,
                              hipStream_t stream) {
  const float* x      = (const float*)d_in[0];
  const float* x_nb   = (const float*)d_in[1];
  const float* weight = (const float*)d_in[2];
  const float* Wx     = (const float*)d_in[3];
  const float* bx     = (const float*)d_in[4];
  const float* Wn     = (const float*)d_in[5];
  const float* bn     = (const float*)d_in[6];
  const float* Ww     = (const float*)d_in[7];
  const float* bw     = (const float*)d_in[8];
  const float* Wl     = (const float*)d_in[9];
  float* out = (float*)d_out;
  const int N = in_sizes[0] / D;  // 50000

  base_mfma<<<dim3(391), dim3(512), 0, stream>>>(x, Wx, bx, bn, bw, out, N);
  // grid 768 = 3 blocks/CU x 256 CU; 25000 tiles -> 32-33 iters/block.
  gnn_mfma<<<dim3(768), dim3(256), 0, stream>>>(x_nb, weight, Wn, Ww, Wl, out, N);
}

// Round 15
// 201.360 us; speedup vs baseline: 1.7086x; 1.7086x over previous
//
#include <hip/hip_runtime.h>

#define D 128
#define KN 32

typedef __bf16 bf16x8 __attribute__((ext_vector_type(8)));
typedef float f32x4 __attribute__((ext_vector_type(4)));

// --- f32 -> bf16 (RNE) packing helpers -------------------------------------
__device__ __forceinline__ unsigned bfpack2(float a, float b) {
  unsigned ua = __float_as_uint(a), ub = __float_as_uint(b);
  ua += 0x7FFFu + ((ua >> 16) & 1u);
  ub += 0x7FFFu + ((ub >> 16) & 1u);
  return (ua >> 16) | (ub & 0xFFFF0000u);
}
__device__ __forceinline__ uint4 pack8(const float4& a, const float4& b) {
  uint4 r;
  r.x = bfpack2(a.x, a.y); r.y = bfpack2(a.z, a.w);
  r.z = bfpack2(b.x, b.y); r.w = bfpack2(b.z, b.w);
  return r;
}

// LDS-only barrier: orders LDS producer/consumer across waves WITHOUT the
// vmcnt(0) drain hipcc emits for __syncthreads(). Keeps prefetch global
// loads in flight across phase boundaries. sched_barrier(0) per rule #18.
__device__ __forceinline__ void lgkm_barrier() {
  __builtin_amdgcn_sched_barrier(0);
  asm volatile("s_waitcnt lgkmcnt(0)" ::: "memory");
  __builtin_amdgcn_s_barrier();
  __builtin_amdgcn_sched_barrier(0);
}

// LDS chunk layout (A and B tiles): buf[row*16 + (slot ^ (row&7))] holds bf16
// of cols slot*8..slot*8+7 of `row`. XOR swizzle -> conflict-free b128 reads.

// 512-thread stager (base_mfma): 128 rows, 2048 chunks -> 4/thread.
__device__ __forceinline__ void stage128_512(const float* __restrict__ src, int nrows,
                                             uint4* buf, int tid) {
  float4 v[4][2];
  #pragma unroll
  for (int i = 0; i < 4; ++i) {
    const int c = i * 512 + tid;
    const int row = c >> 4, slot = c & 15;
    if (row < nrows) {
      const float4* p = (const float4*)(src + (size_t)row * D + slot * 8);
      v[i][0] = p[0]; v[i][1] = p[1];
    } else {
      v[i][0] = make_float4(0.f, 0.f, 0.f, 0.f);
      v[i][1] = make_float4(0.f, 0.f, 0.f, 0.f);
    }
  }
  #pragma unroll
  for (int i = 0; i < 4; ++i) {
    const int c = i * 512 + tid;
    const int row = c >> 4, slot = c & 15;
    buf[row * 16 + (slot ^ (row & 7))] = pack8(v[i][0], v[i][1]);
  }
}

// 256-thread stager: 128 rows (Wn), 2048 chunks -> 8/thread.
__device__ __forceinline__ void stage128_256(const float* __restrict__ src,
                                             uint4* buf, int tid) {
  #pragma unroll
  for (int i = 0; i < 8; ++i) {
    const int c = i * 256 + tid;
    const int row = c >> 4, slot = c & 15;
    const float4* p = (const float4*)(src + (size_t)row * D + slot * 8);
    buf[row * 16 + (slot ^ (row & 7))] = pack8(p[0], p[1]);
  }
}

// 256-thread pipelined stager for the 64-row A-tile: issue / commit halves.
__device__ __forceinline__ void stage64_load(const float* __restrict__ src, int tid,
                                             float4 v[4][2]) {
  #pragma unroll
  for (int i = 0; i < 4; ++i) {
    const int c = i * 256 + tid;
    const int row = c >> 4, slot = c & 15;
    const float4* p = (const float4*)(src + (size_t)row * D + slot * 8);
    v[i][0] = p[0]; v[i][1] = p[1];
  }
}
__device__ __forceinline__ void stage64_write(uint4* buf, int tid,
                                              const float4 v[4][2]) {
  #pragma unroll
  for (int i = 0; i < 4; ++i) {
    const int c = i * 256 + tid;
    const int row = c >> 4, slot = c & 15;
    buf[row * 16 + (slot ^ (row & 7))] = pack8(v[i][0], v[i][1]);
  }
}

// base[r,e] = sum_d x[r,d]*Wx[e,d] + bx[e]+bn[e]+bw[e]  -> d_out
__global__ __launch_bounds__(512, 4) void base_mfma(
    const float* __restrict__ x, const float* __restrict__ Wx,
    const float* __restrict__ bx, const float* __restrict__ bn,
    const float* __restrict__ bw, float* __restrict__ out, int N)
{
  __shared__ uint4 Bb[2048];
  __shared__ uint4 Ab[2048];
  __shared__ float bvec[D];
  const int tid = threadIdx.x;

  stage128_512(Wx, 128, Bb, tid);
  if (tid < D) bvec[tid] = bx[tid] + bn[tid] + bw[tid];

  const int lane = tid & 63, li = lane & 15, g = lane >> 4;
  const int wv = tid >> 6, rq = wv >> 1, ch = wv & 1;
  const int ntiles = (N + 127) >> 7;

  for (int t = blockIdx.x; t < ntiles; t += gridDim.x) {
    const int r0t = t << 7;
    __syncthreads();
    stage128_512(x + (size_t)r0t * D, N - r0t, Ab, tid);
    __syncthreads();

    f32x4 acc[2][4];
    #pragma unroll
    for (int i = 0; i < 2; ++i)
      #pragma unroll
      for (int j = 0; j < 4; ++j) acc[i][j] = (f32x4){0.f, 0.f, 0.f, 0.f};

    #pragma unroll
    for (int kb = 0; kb < 4; ++kb) {
      const int slot = kb * 4 + g;
      const int r0 = rq * 32 + li, r1 = r0 + 16;
      const bf16x8 a0 = __builtin_bit_cast(bf16x8, Ab[r0 * 16 + (slot ^ (r0 & 7))]);
      const bf16x8 a1 = __builtin_bit_cast(bf16x8, Ab[r1 * 16 + (slot ^ (r1 & 7))]);
      #pragma unroll
      for (int ct = 0; ct < 4; ++ct) {
        const int e = ch * 64 + ct * 16 + li;
        const bf16x8 b = __builtin_bit_cast(bf16x8, Bb[e * 16 + (slot ^ (e & 7))]);
        acc[0][ct] = __builtin_amdgcn_mfma_f32_16x16x32_bf16(a0, b, acc[0][ct], 0, 0, 0);
        acc[1][ct] = __builtin_amdgcn_mfma_f32_16x16x32_bf16(a1, b, acc[1][ct], 0, 0, 0);
      }
    }

    #pragma unroll
    for (int rt = 0; rt < 2; ++rt) {
      #pragma unroll
      for (int reg = 0; reg < 4; ++reg) {
        const int r = r0t + rq * 32 + rt * 16 + 4 * g + reg;
        if (r < N) {
          #pragma unroll
          for (int ct = 0; ct < 4; ++ct) {
            const int e = ch * 64 + ct * 16 + li;
            out[(size_t)r * D + e] = acc[rt][ct][reg] + bvec[e];
          }
        }
      }
    }
  }
}

// Fused: 2 nodes/iter, 256 threads, 3 blocks/CU, T14 register prefetch +
// lgkm-only barriers so prefetch loads stay in flight across ALL phases.
// (R9 configuration — best measured: 201.7 us total.)
__global__ __launch_bounds__(256, 3) void gnn_mfma(
    const float* __restrict__ x_nb, const float* __restrict__ weight,
    const float* __restrict__ Wn, const float* __restrict__ Ww,
    const float* __restrict__ Wl, float* __restrict__ out, int N)
{
  __shared__ uint4 Bb[2048];       // Wn bf16, 32 KB
  __shared__ uint4 Ab[1024];       // x_nb tile (2 nodes x 32 nbrs), 16 KB
  __shared__ float basel[2 * D];
  __shared__ float wwl[D], wll[D];
  __shared__ float wgt[2 * KN];
  __shared__ float spart[2][2][KN];
  __shared__ float attnl[2 * KN];
  const int tid = threadIdx.x;

  stage128_256(Wn, Bb, tid);
  if (tid < D) { wwl[tid] = Ww[tid]; wll[tid] = Wl[tid]; }

  const int lane = tid & 63, li = lane & 15, g = lane >> 4;
  const int wv = tid >> 6, rq = wv >> 1, ch = wv & 1;   // node = rq, e-half = ch
  const int ntiles = N >> 1;                             // 25000
  const int gr = gridDim.x;

  float4 v[4][2];
  float basev = 0.f, wgtv = 0.f;

  int t = blockIdx.x;
  {  // prologue: load + commit tile t0
    stage64_load(x_nb + (size_t)(2 * t) * KN * D, tid, v);
    basev = out[(size_t)(2 * t) * D + tid];
    if (tid < 2 * KN) wgtv = weight[(size_t)(2 * t) * KN + tid];
    stage64_write(Ab, tid, v);
    basel[tid] = basev;
    if (tid < 2 * KN) wgt[tid] = wgtv;
  }
  __syncthreads();

  for (; t < ntiles; t += gr) {
    const int tn = t + gr;
    const bool have_next = (tn < ntiles);
    if (have_next) {  // T14 issue: consumed only at the commit below
      stage64_load(x_nb + (size_t)(2 * tn) * KN * D, tid, v);
      basev = out[(size_t)(2 * tn) * D + tid];
      if (tid < 2 * KN) wgtv = weight[(size_t)(2 * tn) * KN + tid];
    }

    // --- MFMA: node rq rows (32), cols ch*64..+63 ---
    f32x4 acc[2][4];
    #pragma unroll
    for (int i = 0; i < 2; ++i)
      #pragma unroll
      for (int j = 0; j < 4; ++j) acc[i][j] = (f32x4){0.f, 0.f, 0.f, 0.f};

    #pragma unroll
    for (int kb = 0; kb < 4; ++kb) {
      const int slot = kb * 4 + g;
      const int r0 = rq * 32 + li, r1 = r0 + 16;
      const bf16x8 a0 = __builtin_bit_cast(bf16x8, Ab[r0 * 16 + (slot ^ (r0 & 7))]);
      const bf16x8 a1 = __builtin_bit_cast(bf16x8, Ab[r1 * 16 + (slot ^ (r1 & 7))]);
      #pragma unroll
      for (int ct = 0; ct < 4; ++ct) {
        const int e = ch * 64 + ct * 16 + li;
        const bf16x8 b = __builtin_bit_cast(bf16x8, Bb[e * 16 + (slot ^ (e & 7))]);
        acc[0][ct] = __builtin_amdgcn_mfma_f32_16x16x32_bf16(a0, b, acc[0][ct], 0, 0, 0);
        acc[1][ct] = __builtin_amdgcn_mfma_f32_16x16x32_bf16(a1, b, acc[1][ct], 0, 0, 0);
      }
    }

    // --- scores: s[k] = sum_e leaky(n_s + base + w*Ww) * Wl ---
    float bvv[4], wwv[4], wlv[4];
    #pragma unroll
    for (int ct = 0; ct < 4; ++ct) {
      const int e = ch * 64 + ct * 16 + li;
      bvv[ct] = basel[rq * D + e];
      wwv[ct] = wwl[e];
      wlv[ct] = wll[e];
    }
    #pragma unroll
    for (int rt = 0; rt < 2; ++rt) {
      #pragma unroll
      for (int reg = 0; reg < 4; ++reg) {
        const int k = rt * 16 + 4 * g + reg;
        const float wk = wgt[rq * KN + k];
        float p = 0.f;
        #pragma unroll
        for (int ct = 0; ct < 4; ++ct) {
          float h = acc[rt][ct][reg] + bvv[ct] + wk * wwv[ct];
          h = fmaxf(h, 0.1f * h);            // LeakyReLU(0.1)
          p = fmaf(h, wlv[ct], p);
        }
        p += __shfl_xor(p, 1);
        p += __shfl_xor(p, 2);
        p += __shfl_xor(p, 4);
        p += __shfl_xor(p, 8);
        if (li == 0) spart[ch][rq][k] = p;
      }
    }
    lgkm_barrier();   // LDS-only: prefetch loads stay in flight

    // --- softmax over K=32 per node (wave 0 handles both nodes) ---
    if (tid < 64) {
      const int node = tid >> 5, k = tid & 31;
      const float s = spart[0][node][k] + spart[1][node][k];
      float mx = s;
      #pragma unroll
      for (int m = 16; m >= 1; m >>= 1) mx = fmaxf(mx, __shfl_xor(mx, m));
      const float pe = __expf(s - mx);
      float sum = pe;
      #pragma unroll
      for (int m = 16; m >= 1; m >>= 1) sum += __shfl_xor(sum, m);
      attnl[node * KN + k] = pe / sum;
    }
    lgkm_barrier();

    // --- epilogue: out[n,c] = sum_k attn[k] * bf16_lds(x_nb)[k][c] ---
    if (wv < 2) {
      const int node = wv;
      const int slot = lane & 15, kg = lane >> 4;
      float p8[8];
      #pragma unroll
      for (int j = 0; j < 8; ++j) p8[j] = 0.f;
      #pragma unroll
      for (int kk = 0; kk < 8; ++kk) {
        const int k = kg * 8 + kk;
        const int row = node * KN + k;
        const uint4 u = Ab[row * 16 + (slot ^ kk)];
        const float a = attnl[node * KN + k];
        const unsigned uw[4] = {u.x, u.y, u.z, u.w};
        #pragma unroll
        for (int q = 0; q < 4; ++q) {
          p8[2 * q]     = fmaf(a, __uint_as_float(uw[q] << 16), p8[2 * q]);
          p8[2 * q + 1] = fmaf(a, __uint_as_float(uw[q] & 0xFFFF0000u), p8[2 * q + 1]);
        }
      }
      #pragma unroll
      for (int j = 0; j < 8; ++j) p8[j] += __shfl_xor(p8[j], 16);
      #pragma unroll
      for (int j = 0; j < 8; ++j) p8[j] += __shfl_xor(p8[j], 32);
      if (kg == 0) {
        float* o = out + (size_t)(2 * t + node) * D + slot * 8;
        *(float4*)(o)     = make_float4(p8[0], p8[1], p8[2], p8[3]);
        *(float4*)(o + 4) = make_float4(p8[4], p8[5], p8[6], p8[7]);
      }
    }
    lgkm_barrier();   // all Ab/attnl reads complete (lgkmcnt covers ds_reads)

    if (have_next) {  // commit next tile (compiler's vmcnt wait lands here)
      stage64_write(Ab, tid, v);
      basel[tid] = basev;
      if (tid < 2 * KN) wgt[tid] = wgtv;
    }
    lgkm_barrier();
  }
}

extern "C" void kernel_launch(void* const* d_in, const int* in_sizes, int n_in,
                              void* d_out, int out_size, void* d_ws, size_t ws_size,
                              hipStream_t stream) {
  const float* x      = (const float*)d_in[0];
  const float* x_nb   = (const float*)d_in[1];
  const float* weight = (const float*)d_in[2];
  const float* Wx     = (const float*)d_in[3];
  const float* bx     = (const float*)d_in[4];
  const float* Wn     = (const float*)d_in[5];
  const float* bn     = (const float*)d_in[6];
  const float* Ww     = (const float*)d_in[7];
  const float* bw     = (const float*)d_in[8];
  const float* Wl     = (const float*)d_in[9];
  float* out = (float*)d_out;
  const int N = in_sizes[0] / D;  // 50000

  base_mfma<<<dim3(391), dim3(512), 0, stream>>>(x, Wx, bx, bn, bw, out, N);
  // grid 768 = 3 blocks/CU x 256 CU; 25000 tiles -> 32-33 iters/block.
  gnn_mfma<<<dim3(768), dim3(256), 0, stream>>>(x_nb, weight, Wn, Ww, Wl, out, N);
}